// Round 20
// baseline (94.917 us; speedup 1.0000x reference)
//
#include <hip/hip_runtime.h>
#include <cmath>

namespace {

constexpr int Dc  = 256;    // channels
constexpr int NB  = 16;     // batch
constexpr int NSP = 1024;   // H*W
constexpr int OC3 = 768;    // 3*D

typedef __attribute__((ext_vector_type(8))) short  short8;
typedef __attribute__((ext_vector_type(8))) ushort ushort8;
typedef __attribute__((ext_vector_type(4))) ushort ushort4_v;
typedef __attribute__((ext_vector_type(4))) float  f32x4;

__device__ inline ushort f2bf(float f) {
  unsigned u = __builtin_bit_cast(unsigned, f);
  unsigned r = (u + 0x7FFFu + ((u >> 16) & 1u)) >> 16;
  return (ushort)r;
}
__device__ inline float bf2f(ushort u) {
  return __builtin_bit_cast(float, (unsigned)u << 16);
}

// 16B global -> LDS DMA (no VGPR round-trip). LDS dest = wave-uniform base +
// lane*16B; global source is per-lane.
__device__ __forceinline__ void dma16(const ushort* g, ushort* l) {
  __builtin_amdgcn_global_load_lds(
      (const __attribute__((address_space(1))) unsigned int*)(const void*)g,
      (__attribute__((address_space(3))) unsigned int*)(void*)l, 16, 0, 0);
}

// ---------------- templated MFMA GEMM core (bf16, fp32 acc), DMA-staged ----
// C[m][n] = sum_k A[m0+m][k]*B[n0+n][k]; tile BM x 128, 4 waves, BK=32.
// Staging via global_load_lds, 3-buffer rotation, counted vmcnt (one
// issue-batch in flight across the barrier; distance-2 cover). Swizzle
// applied on the GLOBAL source (chunk = phys ^ ((row>>1)&3)); LDS linear.
// T5: s_setprio(1) around the MFMA cluster (cross-block wave role-split:
// 2-3 independent blocks/CU at different phases).
// REQUIRES: niter = K/32 >= 2; all A/B rows 16B-aligned.
template<int BM>
__device__ __forceinline__ void mfma_core(
    const ushort* __restrict__ Abase, int lda,
    const ushort* __restrict__ Bbase, int ldb,
    int m0, int n0, int K, f32x4 (&acc)[BM / 32][4])
{
  constexpr int MI    = BM / 32;        // m-frags per wave
  constexpr int AI    = BM / 64;        // A dma16 instrs per wave per step
  constexpr int NLOAD = AI + 2;         // per-thread dma16 per step
  constexpr int BUFSZ = BM * 32 + 128 * 32;   // ushorts per buffer
  __shared__ ushort LDS[3 * BUFSZ];

  const int t = threadIdx.x;
  const int lane = t & 63, wid = t >> 6;
  const int wm = (wid >> 1) * (BM / 2);
  const int wo = (wid & 1) * 64;
  const int lm = lane & 15, lk = lane >> 4;
  const int aph = lk ^ ((lm >> 1) & 3);

  // DMA mapping: one dma16 covers 16 rows (row = r0 + (lane>>2), phys=lane&3);
  // global chunk = phys ^ ((row>>1)&3) pre-applies the swizzle.
  const int lrow = lane >> 2;
  const int niter = K >> 5;

  auto issue = [&](int kk) {
    const int c0 = kk << 5;
    ushort* buf = &LDS[(kk % 3) * BUFSZ];
#pragma unroll
    for (int i = 0; i < AI; ++i) {
      const int r0 = (i * 4 + wid) * 16;
      const int row = r0 + lrow;
      const int chunk = (lane & 3) ^ ((row >> 1) & 3);
      dma16(Abase + (size_t)(m0 + row) * lda + c0 + chunk * 8, buf + r0 * 32);
    }
#pragma unroll
    for (int i = 0; i < 2; ++i) {
      const int r0 = (i * 4 + wid) * 16;
      const int row = r0 + lrow;
      const int chunk = (lane & 3) ^ ((row >> 1) & 3);
      dma16(Bbase + (size_t)(n0 + row) * ldb + c0 + chunk * 8,
            buf + BM * 32 + r0 * 32);
    }
  };

  issue(0);
  issue(1);

  for (int kk = 0; kk < niter; ++kk) {
    __builtin_amdgcn_sched_barrier(0);
    if (kk < niter - 1) {
      if constexpr (NLOAD == 4)
        asm volatile("s_waitcnt vmcnt(4) lgkmcnt(0)" ::: "memory");
      else
        asm volatile("s_waitcnt vmcnt(3) lgkmcnt(0)" ::: "memory");
    } else {
      asm volatile("s_waitcnt vmcnt(0) lgkmcnt(0)" ::: "memory");
    }
    __builtin_amdgcn_s_barrier();
    __builtin_amdgcn_sched_barrier(0);
    if (kk + 2 < niter) issue(kk + 2);

    const ushort* Ab = &LDS[(kk % 3) * BUFSZ];
    const ushort* Bb = Ab + BM * 32;
    short8 af[MI], bw[4];
#pragma unroll
    for (int mi = 0; mi < MI; ++mi)
      af[mi] = *(const short8*)&Ab[(wm + mi * 16 + lm) * 32 + aph * 8];
#pragma unroll
    for (int oi = 0; oi < 4; ++oi)
      bw[oi] = *(const short8*)&Bb[(wo + oi * 16 + lm) * 32 + aph * 8];
    __builtin_amdgcn_s_setprio(1);
#pragma unroll
    for (int mi = 0; mi < MI; ++mi)
#pragma unroll
      for (int oi = 0; oi < 4; ++oi)
        acc[mi][oi] = __builtin_amdgcn_mfma_f32_16x16x32_bf16(
            af[mi], bw[oi], acc[mi][oi], 0, 0, 0);
    __builtin_amdgcn_s_setprio(0);
  }
}

// ---------------- K0prep: merged wb/rowsum + xt transpose + w2b + x1p borders
__global__ __launch_bounds__(256) void k0_prep(
    const float* __restrict__ x, const float* __restrict__ w_qkv,
    const float* __restrict__ w_out,
    ushort* __restrict__ xt, ushort* __restrict__ wb,
    ushort* __restrict__ w2b, float* __restrict__ rowsum,
    ushort* __restrict__ x1p)
{
  __shared__ ushort tr[64][72];
  int bid = blockIdx.x;
  const int t = threadIdx.x;
  if (bid < 768) {
    const int i = bid * 256 + t;
    wb[i] = f2bf(w_qkv[i]);
    if (i < NB * NSP) rowsum[i] = 0.0f;
    return;
  }
  bid -= 768;
  if (bid < 1024) {
    const int b  = bid >> 6;
    const int r  = bid & 63;
    const int c0 = (r >> 4) * 64;
    const int n0 = (r & 15) * 64;
    const float* xb = x + (size_t)b * Dc * NSP;
    const int nl4 = (t & 15) * 4, clb = t >> 4;
#pragma unroll
    for (int rr = 0; rr < 4; ++rr) {
      const int cl = clb + rr * 16;
      float4 xv = *(const float4*)(xb + (size_t)(c0 + cl) * NSP + n0 + nl4);
      tr[nl4 + 0][cl] = f2bf(xv.x);
      tr[nl4 + 1][cl] = f2bf(xv.y);
      tr[nl4 + 2][cl] = f2bf(xv.z);
      tr[nl4 + 3][cl] = f2bf(xv.w);
    }
    __syncthreads();
#pragma unroll
    for (int j = 0; j < 2; ++j) {
      const int s  = t + j * 256;
      const int nl = s >> 3, c8 = (s & 7) * 8;
      *(ushort8*)(xt + ((size_t)(b * NSP + n0 + nl)) * Dc + c0 + c8) =
          *(const ushort8*)&tr[nl][c8];
    }
    return;
  }
  bid -= 1024;
  if (bid < 256) {
    const int o  = bid;
    const int ic = t;
    const float* src = w_out + ((size_t)o * Dc + ic) * 9;
#pragma unroll
    for (int k9 = 0; k9 < 9; ++k9)
      w2b[((size_t)k9 * Dc + o) * Dc + ic] = f2bf(src[k9]);
    return;
  }
  bid -= 256;
  {
    ushort* p = x1p + (size_t)bid * 1156 * 256;
    for (int r = 0; r < 132; ++r) {
      int r34;
      if (r < 34)      r34 = r;                    // h34 = 0
      else if (r < 68) r34 = 33 * 34 + (r - 34);   // h34 = 33
      else { const int rr = r - 68; r34 = (1 + (rr >> 1)) * 34 + (rr & 1) * 33; }
      p[(size_t)r34 * 256 + t] = 0;
    }
  }
}

// ---------------- K1ab: merged qkv projections, XCD-aware decode.
// Each XCD owns 96 consecutive-s blocks = 2 complete batches (48 tiles each:
// 32 q-tiles then 16 v-tiles) -> xt slice (2x512KB) + wb (384KB) L2-resident,
// and the q/v passes share the same cached xt.
__global__ __launch_bounds__(256) void k1ab(
    const ushort* __restrict__ wb, const ushort* __restrict__ xt,
    const float* __restrict__ b_qkv, ushort* __restrict__ qkt,
    ushort* __restrict__ vb)
{
  const int bid = blockIdx.x;
  const int xcd = bid & 7;
  const int s0  = bid >> 3;             // 0..95
  const int b   = xcd + ((s0 / 48) << 3);
  int r = s0 % 48;
  const int t = threadIdx.x, lane = t & 63, wid = t >> 6;
  const int wm = (wid >> 1) * 64, wo = (wid & 1) * 64;
  const int lm = lane & 15, lk = lane >> 4;
  f32x4 acc[4][4];
#pragma unroll
  for (int i = 0; i < 4; ++i)
#pragma unroll
    for (int j = 0; j < 4; ++j) acc[i][j] = (f32x4)(0.0f);

  if (r < 32) {
    const int m0 = (r >> 3) * 128;   // o  (4 tiles)
    const int n0 = (r & 7) * 128;    // n  (8 tiles)
    mfma_core<128>(wb, Dc, xt + (size_t)b * NSP * Dc, Dc, m0, n0, Dc, acc);
    ushort* qb = qkt + (size_t)b * NSP * 512;
#pragma unroll
    for (int mi = 0; mi < 4; ++mi) {
      const int o = m0 + wm + mi * 16 + lk * 4;
      float4 bi = *(const float4*)(b_qkv + o);
#pragma unroll
      for (int oi = 0; oi < 4; ++oi) {
        const int n = n0 + wo + oi * 16 + lm;
        f32x4 a = acc[mi][oi];
        ushort4_v st = { f2bf(a.x + bi.x), f2bf(a.y + bi.y),
                         f2bf(a.z + bi.z), f2bf(a.w + bi.w) };
        *(ushort4_v*)(qb + (size_t)n * 512 + o) = st;
      }
    }
  } else {
    r -= 32;
    const int m0 = (r >> 1) * 128;   // n  (8 tiles)
    const int n0 = (r & 1) * 128;    // c  (2 tiles)
    mfma_core<128>(xt + (size_t)b * NSP * Dc, Dc, wb + 512 * Dc, Dc,
                   m0, n0, Dc, acc);
    ushort* vbb = vb + (size_t)b * Dc * NSP;
#pragma unroll
    for (int oi = 0; oi < 4; ++oi) {
      const int c = n0 + wo + oi * 16 + lm;
      const float bo = b_qkv[512 + c];
#pragma unroll
      for (int mi = 0; mi < 4; ++mi) {
        const int n = m0 + wm + mi * 16 + lk * 4;
        f32x4 a = acc[mi][oi];
        ushort4_v st = { f2bf(a.x + bo), f2bf(a.y + bo),
                         f2bf(a.z + bo), f2bf(a.w + bo) };
        *(ushort4_v*)(vbb + (size_t)c * NSP + n) = st;
      }
    }
  }
}

// ---------------- K2m: E[b][q][k] = bf16(exp(S)), S = 0.0625*sum_c K[c][k]Q[c][q];
// accumulates rowsum[b][q] += sum_k exp(S). 1D grid of 1024 with XCD-aware
// decode: each XCD owns 2 whole batches (E slice 2MB/batch + qkt 1MB fit the
// 4MB per-XCD L2), eliminating cross-XCD re-fetch.
__global__ __launch_bounds__(256) void k2m_exp(
    const ushort* __restrict__ qkt, ushort* __restrict__ E,
    float* __restrict__ rowsum)
{
  const int bid  = blockIdx.x;
  const int xcd  = bid & 7;
  const int s    = bid >> 3;            // 0..127
  const int b    = xcd + ((s >> 6) << 3);
  const int tile = s & 63;
  const int m0 = (tile >> 3) * 128;     // k index
  const int n0 = (tile & 7) * 128;      // q index
  const ushort* base = qkt + (size_t)b * NSP * 512;
  f32x4 acc[4][4];
#pragma unroll
  for (int i = 0; i < 4; ++i)
#pragma unroll
    for (int j = 0; j < 4; ++j) acc[i][j] = (f32x4)(0.0f);
  mfma_core<128>(base + 256, 512, base, 512, m0, n0, Dc, acc);
  const int t = threadIdx.x, lane = t & 63, wid = t >> 6;
  const int wm = (wid >> 1) * 64, wo = (wid & 1) * 64;
  const int lm = lane & 15, lk = lane >> 4;
  ushort* Eb = E + (size_t)b * NSP * NSP;
  float* rs = rowsum + (size_t)b * NSP;
#pragma unroll
  for (int oi = 0; oi < 4; ++oi) {
    const int q = n0 + wo + oi * 16 + lm;
    float ps = 0.0f;
#pragma unroll
    for (int mi = 0; mi < 4; ++mi) {
      const int kidx = m0 + wm + mi * 16 + lk * 4;
      f32x4 a = acc[mi][oi] * 0.0625f;
      float e0 = __expf(a.x), e1 = __expf(a.y);
      float e2 = __expf(a.z), e3 = __expf(a.w);
      ps += (e0 + e1) + (e2 + e3);
      ushort4_v st = { f2bf(e0), f2bf(e1), f2bf(e2), f2bf(e3) };
      *(ushort4_v*)(Eb + (size_t)q * NSP + kidx) = st;
    }
    ps += __shfl_xor(ps, 16);
    ps += __shfl_xor(ps, 32);
    if (lane < 16) atomicAdd(rs + q, ps);
  }
}

// ---------------- K4f: fused PV + softmax-normalize + residual-1 + transpose
// 1D grid of 512 with XCD-aware decode (2 batches per XCD: E 2MB + vb 0.5MB
// per batch L2-resident).
__global__ __launch_bounds__(256) void k4f_pv(
    const ushort* __restrict__ vb, const ushort* __restrict__ E,
    const float* __restrict__ rowsum, const ushort* __restrict__ xt,
    const float* __restrict__ alphap, ushort* __restrict__ x1p)
{
  const int bid  = blockIdx.x;
  const int xcd  = bid & 7;
  const int s0   = bid >> 3;            // 0..63
  const int b    = xcd + ((s0 >> 5) << 3);
  const int tile = s0 & 31;
  const int m0 = (tile >> 3) * 64;      // c (4 tiles)
  const int n0 = (tile & 7) * 128;      // q (8 tiles)
  f32x4 acc[2][4];
#pragma unroll
  for (int i = 0; i < 2; ++i)
#pragma unroll
    for (int j = 0; j < 4; ++j) acc[i][j] = (f32x4)(0.0f);
  mfma_core<64>(vb + (size_t)b * Dc * NSP, NSP,
                E + (size_t)b * NSP * NSP, NSP, m0, n0, NSP, acc);

  __shared__ float T[64][133];   // [c_local][q_local], pad 133
  const int t = threadIdx.x, lane = t & 63, wid = t >> 6;
  const int wm = (wid >> 1) * 32, wo = (wid & 1) * 64;
  const int lm = lane & 15, lk = lane >> 4;
  const float* rs = rowsum + (size_t)b * NSP;
#pragma unroll
  for (int oi = 0; oi < 4; ++oi) {
    const int ql = wo + oi * 16 + lm;
    const float inv = 1.0f / rs[n0 + ql];
#pragma unroll
    for (int mi = 0; mi < 2; ++mi) {
      const int cl = wm + mi * 16 + lk * 4;
      f32x4 a = acc[mi][oi] * inv;
      T[cl + 0][ql] = a.x;
      T[cl + 1][ql] = a.y;
      T[cl + 2][ql] = a.z;
      T[cl + 3][ql] = a.w;
    }
  }
  __syncthreads();

  const float al = *alphap;
  const int sw = wid;           // strip 0..3 (q&3)
  const int c_off = lane;       // 0..63
  const int sp = sw * 256 + m0 + c_off;
  const int r34 = ((sp >> 5) + 1) * 34 + (sp & 31) + 1;
  const int ch0 = n0 >> 2;
  const ushort* xtb = xt + (size_t)b * NSP * Dc + (size_t)sp * Dc + ch0;
  ushort* xpb = x1p + (size_t)b * 1156 * 256;
  ushort8 pack[4];
#pragma unroll
  for (int g = 0; g < 4; ++g) {
    ushort8 xv = *(const ushort8*)(xtb + g * 8);
#pragma unroll
    for (int e = 0; e < 8; ++e) {
      const int chl = g * 8 + e;
      const float v = T[c_off][4 * chl + sw];
      pack[g][e] = f2bf(bf2f(xv[e]) + al * fmaxf(v, 0.f));
    }
  }
  ushort8* dst = (ushort8*)(xpb + (size_t)r34 * 256 + ch0);
#pragma unroll
  for (int g = 0; g < 4; ++g) dst[g] = pack[g];
}

// ---------------- K6: out = x1 + alpha*relu(conv3x3(x1)+b_out)
// MFMA implicit GEMM, BM=64(n) x BN=128(o), BK=64, DMA staging, 3-buffer
// rotation, counted vmcnt(6). XCD-aware decode (each XCD owns 2 batches).
// T5: s_setprio around the MFMA clusters (2 blocks/CU at distinct phases).
__global__ __launch_bounds__(256) void k6_conv_mfma(
    const ushort* __restrict__ x1p, const ushort* __restrict__ w2b,
    const float* __restrict__ bout, const float* __restrict__ alphap,
    float* __restrict__ out)
{
  const int bid  = blockIdx.x;
  const int xcd  = bid & 7;
  const int s0   = bid >> 3;            // 0..63
  const int b    = xcd + ((s0 >> 5) << 3);
  const int tile = s0 & 31;
  const int n0 = (tile & 15) * 64;      // 16 n-tiles
  const int o0 = (tile >> 4) * 128;     // 2 o-tiles
  __shared__ ushort LDS[3 * 12288];  // 3 x (A 4096 ush + W 8192 ush) = 72 KB
  const int t = threadIdx.x;
  const int lane = t & 63, wid = t >> 6;
  const int wm = (wid >> 1) * 32, wo = (wid & 1) * 64;
  const int lm = lane & 15, lk = lane >> 4;
  const int aphr = lm & 7;

  // DMA lane mapping: slot s -> row = s>>3, phys = lane&7;
  // global source chunk = phys ^ (row&7) = (lane&7) ^ (lane>>3).
  const int lrow   = wid * 8 + (lane >> 3);
  const int lchunk = ((lane & 7) ^ (lane >> 3)) * 8;

  const ushort* xp = x1p + (size_t)b * 1156 * 256;
  const int nA0 = n0 + lrow;
  const int r34A0 = ((nA0 >> 5) + 1) * 34 + (nA0 & 31) + 1;
  const ushort* Ag0 = xp + (size_t)r34A0 * 256 + lchunk;        // rows 0..31
  const ushort* Ag1 = Ag0 + (size_t)34 * 256;                   // rows 32..63
  const ushort* Wg  = w2b + (size_t)(o0 + lrow) * 256 + lchunk; // + i*32*256

  auto issue = [&](int kt) {
    const int buf = kt % 3;
    const int k9 = kt >> 2;
    const int dh = ((k9 * 11) >> 5) - 1;
    const int dw = k9 - (dh + 1) * 3 - 1;
    const int aoff = (dh * 34 + dw) * 256 + ((kt & 3) << 6);
    const size_t woff = (size_t)k9 * 65536 + ((kt & 3) << 6);
    ushort* lb = &LDS[buf * 12288 + wid * 512];
    dma16(Ag0 + aoff, lb);
    dma16(Ag1 + aoff, lb + 2048);
#pragma unroll
    for (int i = 0; i < 4; ++i)
      dma16(Wg + woff + i * 8192, lb + 4096 + i * 2048);
  };

  f32x4 acc[2][4];
#pragma unroll
  for (int i = 0; i < 2; ++i)
#pragma unroll
    for (int j = 0; j < 4; ++j) acc[i][j] = (f32x4)(0.0f);

  issue(0);
  issue(1);

  for (int kt = 0; kt < 36; ++kt) {
    __builtin_amdgcn_sched_barrier(0);
    if (kt < 35)
      asm volatile("s_waitcnt vmcnt(6) lgkmcnt(0)" ::: "memory");
    else
      asm volatile("s_waitcnt vmcnt(0) lgkmcnt(0)" ::: "memory");
    __builtin_amdgcn_s_barrier();
    __builtin_amdgcn_sched_barrier(0);
    if (kt + 2 < 36) issue(kt + 2);

    const ushort* Ab = &LDS[(kt % 3) * 12288];
    const ushort* Wb = Ab + 4096;
#pragma unroll
    for (int s = 0; s < 2; ++s) {
      const int ph = ((s << 2) | lk) ^ aphr;
      short8 af[2], bw[4];
#pragma unroll
      for (int mi = 0; mi < 2; ++mi)
        af[mi] = *(const short8*)&Ab[(wm + mi * 16 + lm) * 64 + ph * 8];
#pragma unroll
      for (int oi = 0; oi < 4; ++oi)
        bw[oi] = *(const short8*)&Wb[(wo + oi * 16 + lm) * 64 + ph * 8];
      __builtin_amdgcn_s_setprio(1);
#pragma unroll
      for (int mi = 0; mi < 2; ++mi)
#pragma unroll
        for (int oi = 0; oi < 4; ++oi)
          acc[mi][oi] = __builtin_amdgcn_mfma_f32_16x16x32_bf16(
              af[mi], bw[oi], acc[mi][oi], 0, 0, 0);
      __builtin_amdgcn_s_setprio(0);
    }
  }

  const float al = *alphap;
  float* ob = out + (size_t)b * Dc * NSP;
#pragma unroll
  for (int oi = 0; oi < 4; ++oi) {
    const int o = o0 + wo + oi * 16 + lm;
    const float bo = bout[o];
#pragma unroll
    for (int mi = 0; mi < 2; ++mi) {
      const int nr = n0 + wm + mi * 16 + lk * 4;
      const int r34 = ((nr >> 5) + 1) * 34 + (nr & 31) + 1;
      const ushort* xr = xp + (size_t)r34 * 256 + o;
      f32x4 a = acc[mi][oi];
      float4 r;
      r.x = bf2f(xr[0])   + al * fmaxf(a.x + bo, 0.f);
      r.y = bf2f(xr[256]) + al * fmaxf(a.y + bo, 0.f);
      r.z = bf2f(xr[512]) + al * fmaxf(a.z + bo, 0.f);
      r.w = bf2f(xr[768]) + al * fmaxf(a.w + bo, 0.f);
      *(float4*)(ob + (size_t)o * NSP + nr) = r;
    }
  }
}

}  // namespace

extern "C" void kernel_launch(void* const* d_in, const int* in_sizes, int n_in,
                              void* d_out, int out_size, void* d_ws, size_t ws_size,
                              hipStream_t stream)
{
  const float* x     = (const float*)d_in[0];
  const float* w_qkv = (const float*)d_in[1];
  const float* b_qkv = (const float*)d_in[2];
  const float* w_out = (const float*)d_in[3];
  const float* b_out = (const float*)d_in[4];
  const float* alpha = (const float*)d_in[5];
  float* out = (float*)d_out;

  // Workspace layout (byte offsets), ~77 MB used:
  //   [0,16M)        qkt bf16 [b][n][512]  (dead after k2m)
  //   [16M,24M)      vb  bf16 [b][c][n]    (dead after k4f)
  //   [24M,32M)      xt  bf16 [b][n][c]    (live through k4f)
  //   [32M,+384K)    wb  bf16 [768][256]
  //   [32.5M,+64K)   rowsum fp32 [b][q]
  //   [33M,65M)      E bf16 [b][q][k]      (read by k4f)
  //   [65M,+1.125M)  w2b bf16 [9][o][ic]
  //   [67M,+9.44M)   x1p bf16 [b][1156][256]
  char* ws = (char*)d_ws;
  ushort* qkt  = (ushort*)ws;
  ushort* vb   = (ushort*)(ws + (16u << 20));
  ushort* xt   = (ushort*)(ws + (24u << 20));
  ushort* wb   = (ushort*)(ws + (32u << 20));
  float*  rowsum = (float*)(ws + (32u << 20) + (1u << 19));
  ushort* E    = (ushort*)(ws + (33u << 20));
  ushort* w2b  = (ushort*)(ws + (65u << 20));
  ushort* x1p  = (ushort*)(ws + (67u << 20));

  k0_prep     <<<dim3(2064),       256, 0, stream>>>(x, w_qkv, w_out,
                                                     xt, wb, w2b, rowsum, x1p);
  k1ab        <<<dim3(768),        256, 0, stream>>>(wb, xt, b_qkv, qkt, vb);
  k2m_exp     <<<dim3(1024),       256, 0, stream>>>(qkt, E, rowsum);
  k4f_pv      <<<dim3(512),        256, 0, stream>>>(vb, E, rowsum, xt, alpha, x1p);
  k6_conv_mfma<<<dim3(512),        256, 0, stream>>>(x1p, w2b, b_out, alpha, out);
}

// Round 21
// 94.196 us; speedup vs baseline: 1.0076x; 1.0076x over previous
//
#include <hip/hip_runtime.h>
#include <cmath>

namespace {

constexpr int Dc  = 256;    // channels
constexpr int NB  = 16;     // batch
constexpr int NSP = 1024;   // H*W
constexpr int OC3 = 768;    // 3*D

typedef __attribute__((ext_vector_type(8))) short  short8;
typedef __attribute__((ext_vector_type(8))) ushort ushort8;
typedef __attribute__((ext_vector_type(4))) ushort ushort4_v;
typedef __attribute__((ext_vector_type(4))) float  f32x4;

__device__ inline ushort f2bf(float f) {
  unsigned u = __builtin_bit_cast(unsigned, f);
  unsigned r = (u + 0x7FFFu + ((u >> 16) & 1u)) >> 16;
  return (ushort)r;
}
__device__ inline float bf2f(ushort u) {
  return __builtin_bit_cast(float, (unsigned)u << 16);
}

// 16B global -> LDS DMA (no VGPR round-trip). LDS dest = wave-uniform base +
// lane*16B; global source is per-lane.
__device__ __forceinline__ void dma16(const ushort* g, ushort* l) {
  __builtin_amdgcn_global_load_lds(
      (const __attribute__((address_space(1))) unsigned int*)(const void*)g,
      (__attribute__((address_space(3))) unsigned int*)(void*)l, 16, 0, 0);
}

// ---------------- templated MFMA GEMM core (bf16, fp32 acc), DMA-staged ----
// C[m][n] = sum_k A[m0+m][k]*B[n0+n][k]; tile BM x 128, 4 waves, BK=32.
// Staging via global_load_lds, 3-buffer rotation, counted vmcnt (one
// issue-batch in flight across the barrier; distance-2 cover). Swizzle
// applied on the GLOBAL source (chunk = phys ^ ((row>>1)&3)); LDS linear.
// REQUIRES: niter = K/32 >= 2; all A/B rows 16B-aligned.
template<int BM>
__device__ __forceinline__ void mfma_core(
    const ushort* __restrict__ Abase, int lda,
    const ushort* __restrict__ Bbase, int ldb,
    int m0, int n0, int K, f32x4 (&acc)[BM / 32][4])
{
  constexpr int MI    = BM / 32;        // m-frags per wave
  constexpr int AI    = BM / 64;        // A dma16 instrs per wave per step
  constexpr int NLOAD = AI + 2;         // per-thread dma16 per step
  constexpr int BUFSZ = BM * 32 + 128 * 32;   // ushorts per buffer
  __shared__ ushort LDS[3 * BUFSZ];

  const int t = threadIdx.x;
  const int lane = t & 63, wid = t >> 6;
  const int wm = (wid >> 1) * (BM / 2);
  const int wo = (wid & 1) * 64;
  const int lm = lane & 15, lk = lane >> 4;
  const int aph = lk ^ ((lm >> 1) & 3);

  // DMA mapping: one dma16 covers 16 rows (row = r0 + (lane>>2), phys=lane&3);
  // global chunk = phys ^ ((row>>1)&3) pre-applies the swizzle.
  const int lrow = lane >> 2;
  const int niter = K >> 5;

  auto issue = [&](int kk) {
    const int c0 = kk << 5;
    ushort* buf = &LDS[(kk % 3) * BUFSZ];
#pragma unroll
    for (int i = 0; i < AI; ++i) {
      const int r0 = (i * 4 + wid) * 16;
      const int row = r0 + lrow;
      const int chunk = (lane & 3) ^ ((row >> 1) & 3);
      dma16(Abase + (size_t)(m0 + row) * lda + c0 + chunk * 8, buf + r0 * 32);
    }
#pragma unroll
    for (int i = 0; i < 2; ++i) {
      const int r0 = (i * 4 + wid) * 16;
      const int row = r0 + lrow;
      const int chunk = (lane & 3) ^ ((row >> 1) & 3);
      dma16(Bbase + (size_t)(n0 + row) * ldb + c0 + chunk * 8,
            buf + BM * 32 + r0 * 32);
    }
  };

  issue(0);
  issue(1);

  for (int kk = 0; kk < niter; ++kk) {
    __builtin_amdgcn_sched_barrier(0);
    if (kk < niter - 1) {
      if constexpr (NLOAD == 4)
        asm volatile("s_waitcnt vmcnt(4) lgkmcnt(0)" ::: "memory");
      else
        asm volatile("s_waitcnt vmcnt(3) lgkmcnt(0)" ::: "memory");
    } else {
      asm volatile("s_waitcnt vmcnt(0) lgkmcnt(0)" ::: "memory");
    }
    __builtin_amdgcn_s_barrier();
    __builtin_amdgcn_sched_barrier(0);
    if (kk + 2 < niter) issue(kk + 2);

    const ushort* Ab = &LDS[(kk % 3) * BUFSZ];
    const ushort* Bb = Ab + BM * 32;
    short8 af[MI], bw[4];
#pragma unroll
    for (int mi = 0; mi < MI; ++mi)
      af[mi] = *(const short8*)&Ab[(wm + mi * 16 + lm) * 32 + aph * 8];
#pragma unroll
    for (int oi = 0; oi < 4; ++oi)
      bw[oi] = *(const short8*)&Bb[(wo + oi * 16 + lm) * 32 + aph * 8];
#pragma unroll
    for (int mi = 0; mi < MI; ++mi)
#pragma unroll
      for (int oi = 0; oi < 4; ++oi)
        acc[mi][oi] = __builtin_amdgcn_mfma_f32_16x16x32_bf16(
            af[mi], bw[oi], acc[mi][oi], 0, 0, 0);
  }
}

// ---------------- K0prep: merged wb/rowsum + xt transpose + w2b + x1p borders
__global__ __launch_bounds__(256) void k0_prep(
    const float* __restrict__ x, const float* __restrict__ w_qkv,
    const float* __restrict__ w_out,
    ushort* __restrict__ xt, ushort* __restrict__ wb,
    ushort* __restrict__ w2b, float* __restrict__ rowsum,
    ushort* __restrict__ x1p)
{
  __shared__ ushort tr[64][72];
  int bid = blockIdx.x;
  const int t = threadIdx.x;
  if (bid < 768) {
    const int i = bid * 256 + t;
    wb[i] = f2bf(w_qkv[i]);
    if (i < NB * NSP) rowsum[i] = 0.0f;
    return;
  }
  bid -= 768;
  if (bid < 1024) {
    const int b  = bid >> 6;
    const int r  = bid & 63;
    const int c0 = (r >> 4) * 64;
    const int n0 = (r & 15) * 64;
    const float* xb = x + (size_t)b * Dc * NSP;
    const int nl4 = (t & 15) * 4, clb = t >> 4;
#pragma unroll
    for (int rr = 0; rr < 4; ++rr) {
      const int cl = clb + rr * 16;
      float4 xv = *(const float4*)(xb + (size_t)(c0 + cl) * NSP + n0 + nl4);
      tr[nl4 + 0][cl] = f2bf(xv.x);
      tr[nl4 + 1][cl] = f2bf(xv.y);
      tr[nl4 + 2][cl] = f2bf(xv.z);
      tr[nl4 + 3][cl] = f2bf(xv.w);
    }
    __syncthreads();
#pragma unroll
    for (int j = 0; j < 2; ++j) {
      const int s  = t + j * 256;
      const int nl = s >> 3, c8 = (s & 7) * 8;
      *(ushort8*)(xt + ((size_t)(b * NSP + n0 + nl)) * Dc + c0 + c8) =
          *(const ushort8*)&tr[nl][c8];
    }
    return;
  }
  bid -= 1024;
  if (bid < 256) {
    const int o  = bid;
    const int ic = t;
    const float* src = w_out + ((size_t)o * Dc + ic) * 9;
#pragma unroll
    for (int k9 = 0; k9 < 9; ++k9)
      w2b[((size_t)k9 * Dc + o) * Dc + ic] = f2bf(src[k9]);
    return;
  }
  bid -= 256;
  {
    ushort* p = x1p + (size_t)bid * 1156 * 256;
    for (int r = 0; r < 132; ++r) {
      int r34;
      if (r < 34)      r34 = r;                    // h34 = 0
      else if (r < 68) r34 = 33 * 34 + (r - 34);   // h34 = 33
      else { const int rr = r - 68; r34 = (1 + (rr >> 1)) * 34 + (rr & 1) * 33; }
      p[(size_t)r34 * 256 + t] = 0;
    }
  }
}

// ---------------- K1ab: merged qkv projections, XCD-aware decode.
// Each XCD owns 96 consecutive-s blocks = 2 complete batches (48 tiles each:
// 32 q-tiles then 16 v-tiles) -> xt slice (2x512KB) + wb (384KB) L2-resident,
// and the q/v passes share the same cached xt.
__global__ __launch_bounds__(256) void k1ab(
    const ushort* __restrict__ wb, const ushort* __restrict__ xt,
    const float* __restrict__ b_qkv, ushort* __restrict__ qkt,
    ushort* __restrict__ vb)
{
  const int bid = blockIdx.x;
  const int xcd = bid & 7;
  const int s0  = bid >> 3;             // 0..95
  const int b   = xcd + ((s0 / 48) << 3);
  int r = s0 % 48;
  const int t = threadIdx.x, lane = t & 63, wid = t >> 6;
  const int wm = (wid >> 1) * 64, wo = (wid & 1) * 64;
  const int lm = lane & 15, lk = lane >> 4;
  f32x4 acc[4][4];
#pragma unroll
  for (int i = 0; i < 4; ++i)
#pragma unroll
    for (int j = 0; j < 4; ++j) acc[i][j] = (f32x4)(0.0f);

  if (r < 32) {
    const int m0 = (r >> 3) * 128;   // o  (4 tiles)
    const int n0 = (r & 7) * 128;    // n  (8 tiles)
    mfma_core<128>(wb, Dc, xt + (size_t)b * NSP * Dc, Dc, m0, n0, Dc, acc);
    ushort* qb = qkt + (size_t)b * NSP * 512;
#pragma unroll
    for (int mi = 0; mi < 4; ++mi) {
      const int o = m0 + wm + mi * 16 + lk * 4;
      float4 bi = *(const float4*)(b_qkv + o);
#pragma unroll
      for (int oi = 0; oi < 4; ++oi) {
        const int n = n0 + wo + oi * 16 + lm;
        f32x4 a = acc[mi][oi];
        ushort4_v st = { f2bf(a.x + bi.x), f2bf(a.y + bi.y),
                         f2bf(a.z + bi.z), f2bf(a.w + bi.w) };
        *(ushort4_v*)(qb + (size_t)n * 512 + o) = st;
      }
    }
  } else {
    r -= 32;
    const int m0 = (r >> 1) * 128;   // n  (8 tiles)
    const int n0 = (r & 1) * 128;    // c  (2 tiles)
    mfma_core<128>(xt + (size_t)b * NSP * Dc, Dc, wb + 512 * Dc, Dc,
                   m0, n0, Dc, acc);
    ushort* vbb = vb + (size_t)b * Dc * NSP;
#pragma unroll
    for (int oi = 0; oi < 4; ++oi) {
      const int c = n0 + wo + oi * 16 + lm;
      const float bo = b_qkv[512 + c];
#pragma unroll
      for (int mi = 0; mi < 4; ++mi) {
        const int n = m0 + wm + mi * 16 + lk * 4;
        f32x4 a = acc[mi][oi];
        ushort4_v st = { f2bf(a.x + bo), f2bf(a.y + bo),
                         f2bf(a.z + bo), f2bf(a.w + bo) };
        *(ushort4_v*)(vbb + (size_t)c * NSP + n) = st;
      }
    }
  }
}

// ---------------- K2m: E[b][q][k] = bf16(exp(S)), S = 0.0625*sum_c K[c][k]Q[c][q];
// accumulates rowsum[b][q] += sum_k exp(S). 1D grid of 1024 with XCD-aware
// decode: each XCD owns 2 whole batches (E slice 2MB/batch + qkt 1MB fit the
// 4MB per-XCD L2), eliminating cross-XCD re-fetch.
__global__ __launch_bounds__(256) void k2m_exp(
    const ushort* __restrict__ qkt, ushort* __restrict__ E,
    float* __restrict__ rowsum)
{
  const int bid  = blockIdx.x;
  const int xcd  = bid & 7;
  const int s    = bid >> 3;            // 0..127
  const int b    = xcd + ((s >> 6) << 3);
  const int tile = s & 63;
  const int m0 = (tile >> 3) * 128;     // k index
  const int n0 = (tile & 7) * 128;      // q index
  const ushort* base = qkt + (size_t)b * NSP * 512;
  f32x4 acc[4][4];
#pragma unroll
  for (int i = 0; i < 4; ++i)
#pragma unroll
    for (int j = 0; j < 4; ++j) acc[i][j] = (f32x4)(0.0f);
  mfma_core<128>(base + 256, 512, base, 512, m0, n0, Dc, acc);
  const int t = threadIdx.x, lane = t & 63, wid = t >> 6;
  const int wm = (wid >> 1) * 64, wo = (wid & 1) * 64;
  const int lm = lane & 15, lk = lane >> 4;
  ushort* Eb = E + (size_t)b * NSP * NSP;
  float* rs = rowsum + (size_t)b * NSP;
#pragma unroll
  for (int oi = 0; oi < 4; ++oi) {
    const int q = n0 + wo + oi * 16 + lm;
    float ps = 0.0f;
#pragma unroll
    for (int mi = 0; mi < 4; ++mi) {
      const int kidx = m0 + wm + mi * 16 + lk * 4;
      f32x4 a = acc[mi][oi] * 0.0625f;
      float e0 = __expf(a.x), e1 = __expf(a.y);
      float e2 = __expf(a.z), e3 = __expf(a.w);
      ps += (e0 + e1) + (e2 + e3);
      ushort4_v st = { f2bf(e0), f2bf(e1), f2bf(e2), f2bf(e3) };
      *(ushort4_v*)(Eb + (size_t)q * NSP + kidx) = st;
    }
    ps += __shfl_xor(ps, 16);
    ps += __shfl_xor(ps, 32);
    if (lane < 16) atomicAdd(rs + q, ps);
  }
}

// ---------------- K4f: fused PV + softmax-normalize + residual-1 + transpose
// 1D grid of 512 with XCD-aware decode (2 batches per XCD: E 2MB + vb 0.5MB
// per batch L2-resident).
__global__ __launch_bounds__(256) void k4f_pv(
    const ushort* __restrict__ vb, const ushort* __restrict__ E,
    const float* __restrict__ rowsum, const ushort* __restrict__ xt,
    const float* __restrict__ alphap, ushort* __restrict__ x1p)
{
  const int bid  = blockIdx.x;
  const int xcd  = bid & 7;
  const int s0   = bid >> 3;            // 0..63
  const int b    = xcd + ((s0 >> 5) << 3);
  const int tile = s0 & 31;
  const int m0 = (tile >> 3) * 64;      // c (4 tiles)
  const int n0 = (tile & 7) * 128;      // q (8 tiles)
  f32x4 acc[2][4];
#pragma unroll
  for (int i = 0; i < 2; ++i)
#pragma unroll
    for (int j = 0; j < 4; ++j) acc[i][j] = (f32x4)(0.0f);
  mfma_core<64>(vb + (size_t)b * Dc * NSP, NSP,
                E + (size_t)b * NSP * NSP, NSP, m0, n0, NSP, acc);

  __shared__ float T[64][133];   // [c_local][q_local], pad 133
  const int t = threadIdx.x, lane = t & 63, wid = t >> 6;
  const int wm = (wid >> 1) * 32, wo = (wid & 1) * 64;
  const int lm = lane & 15, lk = lane >> 4;
  const float* rs = rowsum + (size_t)b * NSP;
#pragma unroll
  for (int oi = 0; oi < 4; ++oi) {
    const int ql = wo + oi * 16 + lm;
    const float inv = 1.0f / rs[n0 + ql];
#pragma unroll
    for (int mi = 0; mi < 2; ++mi) {
      const int cl = wm + mi * 16 + lk * 4;
      f32x4 a = acc[mi][oi] * inv;
      T[cl + 0][ql] = a.x;
      T[cl + 1][ql] = a.y;
      T[cl + 2][ql] = a.z;
      T[cl + 3][ql] = a.w;
    }
  }
  __syncthreads();

  const float al = *alphap;
  const int sw = wid;           // strip 0..3 (q&3)
  const int c_off = lane;       // 0..63
  const int sp = sw * 256 + m0 + c_off;
  const int r34 = ((sp >> 5) + 1) * 34 + (sp & 31) + 1;
  const int ch0 = n0 >> 2;
  const ushort* xtb = xt + (size_t)b * NSP * Dc + (size_t)sp * Dc + ch0;
  ushort* xpb = x1p + (size_t)b * 1156 * 256;
  ushort8 pack[4];
#pragma unroll
  for (int g = 0; g < 4; ++g) {
    ushort8 xv = *(const ushort8*)(xtb + g * 8);
#pragma unroll
    for (int e = 0; e < 8; ++e) {
      const int chl = g * 8 + e;
      const float v = T[c_off][4 * chl + sw];
      pack[g][e] = f2bf(bf2f(xv[e]) + al * fmaxf(v, 0.f));
    }
  }
  ushort8* dst = (ushort8*)(xpb + (size_t)r34 * 256 + ch0);
#pragma unroll
  for (int g = 0; g < 4; ++g) dst[g] = pack[g];
}

// ---------------- K6: out = x1 + alpha*relu(conv3x3(x1)+b_out)
// MFMA implicit GEMM, BM=64(n) x BN=128(o), BK=64, DMA staging, 3-buffer
// rotation, counted vmcnt(6). 1D grid of 512 with XCD-aware decode: each
// XCD owns 2 batches (x1p 0.6MB/batch + W 1.1MB -> fully L2-resident).
__global__ __launch_bounds__(256) void k6_conv_mfma(
    const ushort* __restrict__ x1p, const ushort* __restrict__ w2b,
    const float* __restrict__ bout, const float* __restrict__ alphap,
    float* __restrict__ out)
{
  const int bid  = blockIdx.x;
  const int xcd  = bid & 7;
  const int s0   = bid >> 3;            // 0..63
  const int b    = xcd + ((s0 >> 5) << 3);
  const int tile = s0 & 31;
  const int n0 = (tile & 15) * 64;      // 16 n-tiles
  const int o0 = (tile >> 4) * 128;     // 2 o-tiles
  __shared__ ushort LDS[3 * 12288];  // 3 x (A 4096 ush + W 8192 ush) = 72 KB
  const int t = threadIdx.x;
  const int lane = t & 63, wid = t >> 6;
  const int wm = (wid >> 1) * 32, wo = (wid & 1) * 64;
  const int lm = lane & 15, lk = lane >> 4;
  const int aphr = lm & 7;

  // DMA lane mapping: slot s -> row = s>>3, phys = lane&7;
  // global source chunk = phys ^ (row&7) = (lane&7) ^ (lane>>3).
  const int lrow   = wid * 8 + (lane >> 3);
  const int lchunk = ((lane & 7) ^ (lane >> 3)) * 8;

  const ushort* xp = x1p + (size_t)b * 1156 * 256;
  const int nA0 = n0 + lrow;
  const int r34A0 = ((nA0 >> 5) + 1) * 34 + (nA0 & 31) + 1;
  const ushort* Ag0 = xp + (size_t)r34A0 * 256 + lchunk;        // rows 0..31
  const ushort* Ag1 = Ag0 + (size_t)34 * 256;                   // rows 32..63
  const ushort* Wg  = w2b + (size_t)(o0 + lrow) * 256 + lchunk; // + i*32*256

  auto issue = [&](int kt) {
    const int buf = kt % 3;
    const int k9 = kt >> 2;
    const int dh = ((k9 * 11) >> 5) - 1;
    const int dw = k9 - (dh + 1) * 3 - 1;
    const int aoff = (dh * 34 + dw) * 256 + ((kt & 3) << 6);
    const size_t woff = (size_t)k9 * 65536 + ((kt & 3) << 6);
    ushort* lb = &LDS[buf * 12288 + wid * 512];
    dma16(Ag0 + aoff, lb);
    dma16(Ag1 + aoff, lb + 2048);
#pragma unroll
    for (int i = 0; i < 4; ++i)
      dma16(Wg + woff + i * 8192, lb + 4096 + i * 2048);
  };

  f32x4 acc[2][4];
#pragma unroll
  for (int i = 0; i < 2; ++i)
#pragma unroll
    for (int j = 0; j < 4; ++j) acc[i][j] = (f32x4)(0.0f);

  issue(0);
  issue(1);

  for (int kt = 0; kt < 36; ++kt) {
    __builtin_amdgcn_sched_barrier(0);
    if (kt < 35)
      asm volatile("s_waitcnt vmcnt(6) lgkmcnt(0)" ::: "memory");
    else
      asm volatile("s_waitcnt vmcnt(0) lgkmcnt(0)" ::: "memory");
    __builtin_amdgcn_s_barrier();
    __builtin_amdgcn_sched_barrier(0);
    if (kt + 2 < 36) issue(kt + 2);

    const ushort* Ab = &LDS[(kt % 3) * 12288];
    const ushort* Wb = Ab + 4096;
#pragma unroll
    for (int s = 0; s < 2; ++s) {
      const int ph = ((s << 2) | lk) ^ aphr;
      short8 af[2], bw[4];
#pragma unroll
      for (int mi = 0; mi < 2; ++mi)
        af[mi] = *(const short8*)&Ab[(wm + mi * 16 + lm) * 64 + ph * 8];
#pragma unroll
      for (int oi = 0; oi < 4; ++oi)
        bw[oi] = *(const short8*)&Wb[(wo + oi * 16 + lm) * 64 + ph * 8];
#pragma unroll
      for (int mi = 0; mi < 2; ++mi)
#pragma unroll
        for (int oi = 0; oi < 4; ++oi)
          acc[mi][oi] = __builtin_amdgcn_mfma_f32_16x16x32_bf16(
              af[mi], bw[oi], acc[mi][oi], 0, 0, 0);
    }
  }

  const float al = *alphap;
  float* ob = out + (size_t)b * Dc * NSP;
#pragma unroll
  for (int oi = 0; oi < 4; ++oi) {
    const int o = o0 + wo + oi * 16 + lm;
    const float bo = bout[o];
#pragma unroll
    for (int mi = 0; mi < 2; ++mi) {
      const int nr = n0 + wm + mi * 16 + lk * 4;
      const int r34 = ((nr >> 5) + 1) * 34 + (nr & 31) + 1;
      const ushort* xr = xp + (size_t)r34 * 256 + o;
      f32x4 a = acc[mi][oi];
      float4 r;
      r.x = bf2f(xr[0])   + al * fmaxf(a.x + bo, 0.f);
      r.y = bf2f(xr[256]) + al * fmaxf(a.y + bo, 0.f);
      r.z = bf2f(xr[512]) + al * fmaxf(a.z + bo, 0.f);
      r.w = bf2f(xr[768]) + al * fmaxf(a.w + bo, 0.f);
      *(float4*)(ob + (size_t)o * NSP + nr) = r;
    }
  }
}

}  // namespace

extern "C" void kernel_launch(void* const* d_in, const int* in_sizes, int n_in,
                              void* d_out, int out_size, void* d_ws, size_t ws_size,
                              hipStream_t stream)
{
  const float* x     = (const float*)d_in[0];
  const float* w_qkv = (const float*)d_in[1];
  const float* b_qkv = (const float*)d_in[2];
  const float* w_out = (const float*)d_in[3];
  const float* b_out = (const float*)d_in[4];
  const float* alpha = (const float*)d_in[5];
  float* out = (float*)d_out;

  // Workspace layout (byte offsets), ~77 MB used:
  //   [0,16M)        qkt bf16 [b][n][512]  (dead after k2m)
  //   [16M,24M)      vb  bf16 [b][c][n]    (dead after k4f)
  //   [24M,32M)      xt  bf16 [b][n][c]    (live through k4f)
  //   [32M,+384K)    wb  bf16 [768][256]
  //   [32.5M,+64K)   rowsum fp32 [b][q]
  //   [33M,65M)      E bf16 [b][q][k]      (read by k4f)
  //   [65M,+1.125M)  w2b bf16 [9][o][ic]
  //   [67M,+9.44M)   x1p bf16 [b][1156][256]
  char* ws = (char*)d_ws;
  ushort* qkt  = (ushort*)ws;
  ushort* vb   = (ushort*)(ws + (16u << 20));
  ushort* xt   = (ushort*)(ws + (24u << 20));
  ushort* wb   = (ushort*)(ws + (32u << 20));
  float*  rowsum = (float*)(ws + (32u << 20) + (1u << 19));
  ushort* E    = (ushort*)(ws + (33u << 20));
  ushort* w2b  = (ushort*)(ws + (65u << 20));
  ushort* x1p  = (ushort*)(ws + (67u << 20));

  k0_prep     <<<dim3(2064),       256, 0, stream>>>(x, w_qkv, w_out,
                                                     xt, wb, w2b, rowsum, x1p);
  k1ab        <<<dim3(768),        256, 0, stream>>>(wb, xt, b_qkv, qkt, vb);
  k2m_exp     <<<dim3(1024),       256, 0, stream>>>(qkt, E, rowsum);
  k4f_pv      <<<dim3(512),        256, 0, stream>>>(vb, E, rowsum, xt, alpha, x1p);
  k6_conv_mfma<<<dim3(512),        256, 0, stream>>>(x1p, w2b, b_out, alpha, out);
}